// Round 1
// baseline (169.574 us; speedup 1.0000x reference)
//
#include <hip/hip_runtime.h>
#include <hip/hip_bf16.h>

// ---------------------------------------------------------------------------
// GCN layer: out = D^{-1/2} (A_set + I) D^{-1/2} @ (x @ W) + bias
// Pipeline (4 dispatches):
//   memset mask (8MB)
//   fused_front: [build_adj (fire-and-forget atomicOr bitmask)
//                 | cast x->bf16 | transpose W | zero Hs pad row + dinv[M]]
//   fused_mid: [gemm 64x64 MFMA BK=64 (B staged with XOR-swizzled source so
//               the B ds_read_b128 is conflict-free; was 16-way same-bank)
//               | build_ell: mask -> ELL list (+self entry, zero-row pads)]
//   spmm: XCD-sliced. D split into 8 column-slices of 64; slice =
//     blockIdx.x % 8 (linear block IDs round-robin over the 8 XCDs) so each
//     XCD's gather working set is ONE 1MB column-slice of Hs -> fully
//     L2-resident (was 8MB/XCD -> L3 thrash). 8-lane group per ELL entry,
//     8 entries in flight per wave; (j, dinv[j]) staged once per wave in LDS.
// ---------------------------------------------------------------------------

#define ELL_STRIDE 128

typedef __attribute__((ext_vector_type(8))) short bf16x8;
typedef __attribute__((ext_vector_type(4))) float f32x4;

__device__ __forceinline__ unsigned short f2bf(float f) {
  unsigned u = __float_as_uint(f);
  u = (u + 0x7fff + ((u >> 16) & 1)) >> 16;  // RNE
  return (unsigned short)u;
}
__device__ __forceinline__ float bflo(unsigned u) {
  return __uint_as_float(u << 16);
}
__device__ __forceinline__ float bfhi(unsigned u) {
  return __uint_as_float(u & 0xffff0000u);
}

// ---- fused front-end:
// [0,eb): build_adj  [eb,eb+cb): cast  [..+tb): transpose  [last]: pad row
__global__ __launch_bounds__(256) void fused_front_kernel(
    const int* __restrict__ ei, unsigned* __restrict__ mask, int n_edges,
    int words,
    const float* __restrict__ x, unsigned short* __restrict__ xb, int n4,
    const float* __restrict__ W, unsigned short* __restrict__ Wt, int K, int N,
    unsigned short* __restrict__ Hs, float* __restrict__ dinv, int n_nodes,
    int edge_blocks, int cast_blocks, int tr_blocks) {
  const int bid = blockIdx.x;
  if (bid < edge_blocks) {
    const int e = bid * 256 + threadIdx.x;
    if (e < n_edges) {
      const int u = ei[e];
      const int v = ei[e + n_edges];
      // fire-and-forget: never use the return value
      atomicOr(&mask[(size_t)u * words + (v >> 5)], 1u << (v & 31));
      atomicOr(&mask[(size_t)v * words + (u >> 5)], 1u << (u & 31));
    }
    return;
  }
  if (bid < edge_blocks + cast_blocks) {
    const int t = (bid - edge_blocks) * 256 + threadIdx.x;
    if (t < n4) {
      float4 v = ((const float4*)x)[t];
      ushort4 o;
      o.x = f2bf(v.x); o.y = f2bf(v.y); o.z = f2bf(v.z); o.w = f2bf(v.w);
      ((ushort4*)xb)[t] = o;
    }
    return;
  }
  if (bid < edge_blocks + cast_blocks + tr_blocks) {
    // transpose+cast: W[K][N] fp32 -> Wt[N][K] bf16, 32x32 tiles
    __shared__ float tile[32][33];
    const int b = bid - edge_blocks - cast_blocks;
    const int bx = b & ((N >> 5) - 1);
    const int by = b >> (31 - __builtin_clz(N >> 5));
    const int tx = threadIdx.x & 31;
    const int ty = threadIdx.x >> 5;  // 0..7
#pragma unroll
    for (int r = 0; r < 4; ++r)
      tile[ty + 8 * r][tx] = W[(size_t)(by * 32 + ty + 8 * r) * N + bx * 32 + tx];
    __syncthreads();
#pragma unroll
    for (int r = 0; r < 4; ++r)
      Wt[(size_t)(bx * 32 + ty + 8 * r) * K + by * 32 + tx] =
          f2bf(tile[tx][ty + 8 * r]);
    return;
  }
  // zero the ELL pad row Hs[n_nodes][:] and its scale dinv[n_nodes]
  {
    const int t = threadIdx.x;
    if (t < (N >> 1)) ((unsigned*)(Hs + (size_t)n_nodes * N))[t] = 0;
    if (t == 0) dinv[n_nodes] = 0.f;
  }
}

// ---- fused mid: [0,gb): gemm 64x64 BK=64   [gb..): build_ell (wave/node)
__global__ __launch_bounds__(256) void fused_mid_kernel(
    const unsigned short* __restrict__ xb,  // [M][K] bf16
    const unsigned short* __restrict__ Wt,  // [N][K] bf16
    unsigned short* __restrict__ Hs,        // [M+1][N] bf16 (unscaled)
    const unsigned* __restrict__ mask, unsigned short* __restrict__ ell,
    int* __restrict__ deg, float* __restrict__ dinv,
    int M, int N, int K, int words, int gemm_blocks, int nbx_sh) {
  // A slot s: kc=s>>6 (8B k-chunk), row=s&63 -> xb[m0+row][k0+kc*8]
  // B slot s: n=s>>3, kc=s&7  -- STORED with kc XOR (n&7) source pre-swizzle
  //   so the fragment read (stride-128B across lanes, was 16-way same-bank)
  //   lands on 8 distinct bank-quads (2-way = free). global_load_lds forces a
  //   linear LDS dest, so the swizzle must be applied on the global source
  //   and the ds_read address (both-sides-or-neither).
  __shared__ unsigned short As[512 * 8];
  __shared__ unsigned short Bs[512 * 8];

  const int tid = threadIdx.x;
  const int bid = blockIdx.x;

  if (bid < gemm_blocks) {
    const int wave = tid >> 6;
    const int lane = tid & 63;
    const int q = lane >> 4;   // quad
    const int c = lane & 15;
    const int bx = bid & ((1 << nbx_sh) - 1);
    const int by = bid >> nbx_sh;
    const int m0 = by * 64;
    const int n0 = bx * 64;
    const int wr = wave >> 1, wc = wave & 1;

    f32x4 acc[2][2] = {};

    for (int k0 = 0; k0 < K; k0 += 64) {
#pragma unroll
      for (int t = 0; t < 2; ++t) {
        const int sbase = t * 256 + wave * 64;
        const int s = sbase + lane;
        const unsigned short* g =
            xb + (size_t)(m0 + (s & 63)) * K + k0 + (s >> 6) * 8;
        __builtin_amdgcn_global_load_lds(
            (const __attribute__((address_space(1))) void*)g,
            (__attribute__((address_space(3))) void*)(As + sbase * 8), 16, 0, 0);
      }
#pragma unroll
      for (int t = 0; t < 2; ++t) {
        const int sbase = t * 256 + wave * 64;
        const int s = sbase + lane;
        const int bn = s >> 3;
        const int bk = (s & 7) ^ (bn & 7);  // XOR-swizzled source (same 128B seg)
        const unsigned short* g =
            Wt + (size_t)(n0 + bn) * K + k0 + bk * 8;
        __builtin_amdgcn_global_load_lds(
            (const __attribute__((address_space(1))) void*)g,
            (__attribute__((address_space(3))) void*)(Bs + sbase * 8), 16, 0, 0);
      }
      __syncthreads();

#pragma unroll
      for (int kk = 0; kk < 2; ++kk) {
        bf16x8 a[2], b[2];
#pragma unroll
        for (int tm = 0; tm < 2; ++tm) {
          const int row = wr * 32 + tm * 16 + c;
          a[tm] = *(const bf16x8*)(As + (((kk * 4 + q) * 64) + row) * 8);
        }
#pragma unroll
        for (int tn = 0; tn < 2; ++tn) {
          const int n = wc * 32 + tn * 16 + c;
          b[tn] = *(const bf16x8*)(Bs + (n * 8 + ((kk * 4 + q) ^ (n & 7))) * 8);
        }
#pragma unroll
        for (int tm = 0; tm < 2; ++tm)
#pragma unroll
          for (int tn = 0; tn < 2; ++tn)
            acc[tm][tn] = __builtin_amdgcn_mfma_f32_16x16x32_bf16(
                a[tm], b[tn], acc[tm][tn], 0, 0, 0);
      }
      __syncthreads();
    }

    // C/D mapping: col=lane&15, row=quad*4+reg ; unscaled store
#pragma unroll
    for (int tm = 0; tm < 2; ++tm) {
#pragma unroll
      for (int r = 0; r < 4; ++r) {
        const int grow = m0 + wr * 32 + tm * 16 + q * 4 + r;
#pragma unroll
        for (int tn = 0; tn < 2; ++tn) {
          const int gcol = n0 + wc * 32 + tn * 16 + c;
          Hs[(size_t)grow * N + gcol] = f2bf(acc[tm][tn][r]);
        }
      }
    }
    return;
  }

  // ---- build_ell: one wave per node, popcount + lane prefix-scan.
  {
    const int wave = tid >> 6, lane = tid & 63;
    const int node = (bid - gemm_blocks) * 4 + wave;
    const unsigned* __restrict__ row = mask + (size_t)node * words;
    unsigned short* __restrict__ out = ell + (size_t)node * ELL_STRIDE;

    int running = 0;
    for (int r = 0; r < words; r += 64) {
      const int w = r + lane;
      unsigned bits = row[w];
      const int cnt = __popc(bits);
      int x = cnt;
#pragma unroll
      for (int d = 1; d < 64; d <<= 1) {
        int y = __shfl_up(x, d, 64);
        if (lane >= d) x += y;
      }
      int pos = running + x - cnt;
      while (bits) {
        const int b = __builtin_ctz(bits);
        bits &= bits - 1;
        if (pos < ELL_STRIDE) out[pos] = (unsigned short)((w << 5) + b);
        ++pos;
      }
      running += __shfl(x, 63, 64);
    }
    // self entry at [running], pads (index M -> dinv 0, zero row) after
    for (int p = running + lane; p < ELL_STRIDE; p += 64)
      out[p] = (unsigned short)(p == running ? node : M);
    if (lane == 0) {
      const int dd = running + 1;  // + self
      deg[node] = dd < ELL_STRIDE ? dd : ELL_STRIDE;
      dinv[node] = rsqrtf((float)running + 1.0f);
    }
  }
}

// ---- spmm: 1D grid of 8*(n/4) blocks. slice = blockIdx.x % 8 -> one XCD
// (linear block IDs round-robin across the 8 XCDs), so each XCD's gather
// working set is Hs columns [slice*64, slice*64+64) for all rows = 1MB,
// L2-resident. Wave = one node; 8-lane group per ELL entry (16B/lane),
// 8 entries per iter. (j, dinv[j]) staged once per wave as packed uint2 in
// LDS -> one ds_read_b64 per group per iter, no global loads on the gather
// critical path. shfl_xor(8/16/32) reduce across the 8 groups.
__global__ __launch_bounds__(256) void spmm_kernel(
    const unsigned short* __restrict__ ell, const int* __restrict__ deg,
    const float* __restrict__ dinv, const unsigned short* __restrict__ Hs,
    const float* __restrict__ bias, float* __restrict__ out, int n, int D) {
  __shared__ uint2 ji[4][ELL_STRIDE];
  const int wave = threadIdx.x >> 6, lane = threadIdx.x & 63;
  const int slice = blockIdx.x & 7;   // XCD-pinned D-slice
  const int grp = blockIdx.x >> 3;
  const int i = grp * 4 + wave;       // n divisible by 4
  const int e = lane >> 3, c = lane & 7;
  const int Ds = D >> 3;              // 64 cols per slice

  {  // stage (j, dinv[j]) — 2 entries per lane, scattered loads pipelined
    const unsigned j0 = ell[(size_t)i * ELL_STRIDE + lane];
    const unsigned j1 = ell[(size_t)i * ELL_STRIDE + 64 + lane];
    ji[wave][lane] = make_uint2(j0, __float_as_uint(dinv[j0]));
    ji[wave][64 + lane] = make_uint2(j1, __float_as_uint(dinv[j1]));
  }
  const int d = deg[i];            // includes the self entry
  const float di = dinv[i];
  const int kmax = (d + 7) & ~7;   // pads (dinv 0, zero row) cover the tail

  const unsigned short* __restrict__ hb = Hs + slice * Ds + c * 8;
  float acc[8] = {0.f, 0.f, 0.f, 0.f, 0.f, 0.f, 0.f, 0.f};

#pragma unroll 4
  for (int k = 0; k < kmax; k += 8) {
    const uint2 t = ji[wave][k + e];  // 8 addrs/wave, 8-lane broadcast each
    const int j = t.x;
    const float dj = __uint_as_float(t.y);
    const uint4 hv = *(const uint4*)(hb + (size_t)j * D);
    acc[0] += dj * bflo(hv.x); acc[1] += dj * bfhi(hv.x);
    acc[2] += dj * bflo(hv.y); acc[3] += dj * bfhi(hv.y);
    acc[4] += dj * bflo(hv.z); acc[5] += dj * bfhi(hv.z);
    acc[6] += dj * bflo(hv.w); acc[7] += dj * bfhi(hv.w);
  }
#pragma unroll
  for (int t = 0; t < 8; ++t) {
    acc[t] += __shfl_xor(acc[t], 8, 64);
    acc[t] += __shfl_xor(acc[t], 16, 64);
    acc[t] += __shfl_xor(acc[t], 32, 64);
  }

  if (lane < 8) {  // lane = c, e == 0
    const float4 b0 = *(const float4*)(bias + slice * Ds + lane * 8);
    const float4 b1 = *(const float4*)(bias + slice * Ds + lane * 8 + 4);
    float* op = out + (size_t)i * D + slice * Ds + lane * 8;
    float4 o0, o1;
    o0.x = di * acc[0] + b0.x; o0.y = di * acc[1] + b0.y;
    o0.z = di * acc[2] + b0.z; o0.w = di * acc[3] + b0.w;
    o1.x = di * acc[4] + b1.x; o1.y = di * acc[5] + b1.y;
    o1.z = di * acc[6] + b1.z; o1.w = di * acc[7] + b1.w;
    *(float4*)op = o0;
    *(float4*)(op + 4) = o1;
  }
}

extern "C" void kernel_launch(void* const* d_in, const int* in_sizes, int n_in,
                              void* d_out, int out_size, void* d_ws, size_t ws_size,
                              hipStream_t stream) {
  const float* x    = (const float*)d_in[0];
  const int*   ei   = (const int*)d_in[1];
  const float* W    = (const float*)d_in[2];
  const float* bias = (const float*)d_in[3];
  float* out = (float*)d_out;

  const int d_out_dim = in_sizes[3];             // 512
  const int d_in_dim  = in_sizes[2] / d_out_dim; // 512
  const int n_nodes   = in_sizes[0] / d_in_dim;  // 8192
  const int n_edges   = in_sizes[1] / 2;         // 262144
  const int words     = (n_nodes + 31) / 32;     // 256

  // workspace layout (bytes)
  char* ws = (char*)d_ws;
  size_t off = 0;
  unsigned* mask = (unsigned*)(ws + off); off += (size_t)n_nodes * words * 4;       // 8 MB
  int* deg       = (int*)(ws + off);      off += (size_t)n_nodes * 4;               // 32 KB
  float* dinv    = (float*)(ws + off);    off += (size_t)(n_nodes + 1) * 4;         // 32 KB + pad
  unsigned short* ell = (unsigned short*)(ws + off); off += (size_t)n_nodes * ELL_STRIDE * 2; // 2 MB
  unsigned short* xb  = (unsigned short*)(ws + off); off += (size_t)n_nodes * d_in_dim * 2;   // 8 MB
  unsigned short* Wt  = (unsigned short*)(ws + off); off += (size_t)d_in_dim * d_out_dim * 2; // 512 KB
  unsigned short* Hs  = (unsigned short*)(ws + off);
  off += (size_t)(n_nodes + 1) * d_out_dim * 2;  // 8 MB + pad row

  hipMemsetAsync(mask, 0, (size_t)n_nodes * words * 4, stream);

  const int edge_blocks = (n_edges + 255) / 256;              // 1024
  const int n4 = n_nodes * d_in_dim / 4;
  const int cast_blocks = (n4 + 255) / 256;                   // 4096
  const int tr_blocks = (d_in_dim / 32) * (d_out_dim / 32);   // 256
  fused_front_kernel<<<edge_blocks + cast_blocks + tr_blocks + 1, 256, 0, stream>>>(
      ei, mask, n_edges, words, x, xb, n4, W, Wt, d_in_dim, d_out_dim,
      Hs, dinv, n_nodes, edge_blocks, cast_blocks, tr_blocks);

  const int nbx = d_out_dim / 64;                             // 8
  const int nbx_sh = 31 - __builtin_clz(nbx);                 // 3
  const int gemm_blocks = nbx * (n_nodes / 64);               // 1024
  const int ell_blocks = n_nodes / 4;                         // 2048
  fused_mid_kernel<<<gemm_blocks + ell_blocks, 256, 0, stream>>>(
      xb, Wt, Hs, mask, ell, deg, dinv,
      n_nodes, d_out_dim, d_in_dim, words, gemm_blocks, nbx_sh);

  const int spmm_blocks = 8 * (n_nodes / 4);                  // 16384
  spmm_kernel<<<spmm_blocks, 256, 0, stream>>>(ell, deg, dinv, Hs, bias, out,
                                               n_nodes, d_out_dim);
}

// Round 2
// 160.643 us; speedup vs baseline: 1.0556x; 1.0556x over previous
//
#include <hip/hip_runtime.h>
#include <hip/hip_bf16.h>

// ---------------------------------------------------------------------------
// GCN layer: out = D^{-1/2} (A_set + I) D^{-1/2} @ (x @ W) + bias
// Pipeline (4 dispatches):
//   memset mask (8MB)
//   fused_front: [build_adj (fire-and-forget atomicOr bitmask)
//                 | cast x->bf16 | transpose W | zero Hs pad row + dinv[M]]
//   fused_mid: [gemm 64x64 MFMA BK=64 (B staged with XOR-swizzled source so
//               the B ds_read_b128 is conflict-free; was 16-way same-bank)
//               | build_ell: mask -> ELL list (+self entry, zero-row pads)]
//   spmm: ONE WAVE PER NODE, FULL D row per entry (64 lanes x 16B = 1KB =
//     one Hs row, fully coalesced). Round-1 lesson: the gather is cache-
//     served (FETCH 16MB, HBM 7%) -> locality slicing only multiplied the
//     staging overhead. This shape instead amortizes staging once per node,
//     runs ~66 iters/wave for latency hiding, needs NO cross-lane reduce,
//     and stages (byte_offset, dinv_j) so per-iter addressing is one add.
// ---------------------------------------------------------------------------

#define ELL_STRIDE 128

typedef __attribute__((ext_vector_type(8))) short bf16x8;
typedef __attribute__((ext_vector_type(4))) float f32x4;

__device__ __forceinline__ unsigned short f2bf(float f) {
  unsigned u = __float_as_uint(f);
  u = (u + 0x7fff + ((u >> 16) & 1)) >> 16;  // RNE
  return (unsigned short)u;
}
__device__ __forceinline__ float bflo(unsigned u) {
  return __uint_as_float(u << 16);
}
__device__ __forceinline__ float bfhi(unsigned u) {
  return __uint_as_float(u & 0xffff0000u);
}

// ---- fused front-end:
// [0,eb): build_adj  [eb,eb+cb): cast  [..+tb): transpose  [last]: pad row
__global__ __launch_bounds__(256) void fused_front_kernel(
    const int* __restrict__ ei, unsigned* __restrict__ mask, int n_edges,
    int words,
    const float* __restrict__ x, unsigned short* __restrict__ xb, int n4,
    const float* __restrict__ W, unsigned short* __restrict__ Wt, int K, int N,
    unsigned short* __restrict__ Hs, float* __restrict__ dinv, int n_nodes,
    int edge_blocks, int cast_blocks, int tr_blocks) {
  const int bid = blockIdx.x;
  if (bid < edge_blocks) {
    const int e = bid * 256 + threadIdx.x;
    if (e < n_edges) {
      const int u = ei[e];
      const int v = ei[e + n_edges];
      // fire-and-forget: never use the return value
      atomicOr(&mask[(size_t)u * words + (v >> 5)], 1u << (v & 31));
      atomicOr(&mask[(size_t)v * words + (u >> 5)], 1u << (u & 31));
    }
    return;
  }
  if (bid < edge_blocks + cast_blocks) {
    const int t = (bid - edge_blocks) * 256 + threadIdx.x;
    if (t < n4) {
      float4 v = ((const float4*)x)[t];
      ushort4 o;
      o.x = f2bf(v.x); o.y = f2bf(v.y); o.z = f2bf(v.z); o.w = f2bf(v.w);
      ((ushort4*)xb)[t] = o;
    }
    return;
  }
  if (bid < edge_blocks + cast_blocks + tr_blocks) {
    // transpose+cast: W[K][N] fp32 -> Wt[N][K] bf16, 32x32 tiles
    __shared__ float tile[32][33];
    const int b = bid - edge_blocks - cast_blocks;
    const int bx = b & ((N >> 5) - 1);
    const int by = b >> (31 - __builtin_clz(N >> 5));
    const int tx = threadIdx.x & 31;
    const int ty = threadIdx.x >> 5;  // 0..7
#pragma unroll
    for (int r = 0; r < 4; ++r)
      tile[ty + 8 * r][tx] = W[(size_t)(by * 32 + ty + 8 * r) * N + bx * 32 + tx];
    __syncthreads();
#pragma unroll
    for (int r = 0; r < 4; ++r)
      Wt[(size_t)(bx * 32 + ty + 8 * r) * K + by * 32 + tx] =
          f2bf(tile[tx][ty + 8 * r]);
    return;
  }
  // zero the ELL pad row Hs[n_nodes][:] and its scale dinv[n_nodes]
  {
    const int t = threadIdx.x;
    if (t < (N >> 1)) ((unsigned*)(Hs + (size_t)n_nodes * N))[t] = 0;
    if (t == 0) dinv[n_nodes] = 0.f;
  }
}

// ---- fused mid: [0,gb): gemm 64x64 BK=64   [gb..): build_ell (wave/node)
__global__ __launch_bounds__(256) void fused_mid_kernel(
    const unsigned short* __restrict__ xb,  // [M][K] bf16
    const unsigned short* __restrict__ Wt,  // [N][K] bf16
    unsigned short* __restrict__ Hs,        // [M+1][N] bf16 (unscaled)
    const unsigned* __restrict__ mask, unsigned short* __restrict__ ell,
    int* __restrict__ deg, float* __restrict__ dinv,
    int M, int N, int K, int words, int gemm_blocks, int nbx_sh) {
  // A slot s: kc=s>>6 (8B k-chunk), row=s&63 -> xb[m0+row][k0+kc*8]
  // B slot s: n=s>>3, kc=s&7  -- STORED with kc XOR (n&7) source pre-swizzle
  //   so the fragment read (stride-128B across lanes, was 16-way same-bank)
  //   spans all 8 bank-quads (both-sides-or-neither swizzle: global source
  //   pre-swizzled because global_load_lds forces a linear LDS dest).
  __shared__ unsigned short As[512 * 8];
  __shared__ unsigned short Bs[512 * 8];

  const int tid = threadIdx.x;
  const int bid = blockIdx.x;

  if (bid < gemm_blocks) {
    const int wave = tid >> 6;
    const int lane = tid & 63;
    const int q = lane >> 4;   // quad
    const int c = lane & 15;
    const int bx = bid & ((1 << nbx_sh) - 1);
    const int by = bid >> nbx_sh;
    const int m0 = by * 64;
    const int n0 = bx * 64;
    const int wr = wave >> 1, wc = wave & 1;

    f32x4 acc[2][2] = {};

    for (int k0 = 0; k0 < K; k0 += 64) {
#pragma unroll
      for (int t = 0; t < 2; ++t) {
        const int sbase = t * 256 + wave * 64;
        const int s = sbase + lane;
        const unsigned short* g =
            xb + (size_t)(m0 + (s & 63)) * K + k0 + (s >> 6) * 8;
        __builtin_amdgcn_global_load_lds(
            (const __attribute__((address_space(1))) void*)g,
            (__attribute__((address_space(3))) void*)(As + sbase * 8), 16, 0, 0);
      }
#pragma unroll
      for (int t = 0; t < 2; ++t) {
        const int sbase = t * 256 + wave * 64;
        const int s = sbase + lane;
        const int bn = s >> 3;
        const int bk = (s & 7) ^ (bn & 7);  // XOR-swizzled source (same 128B seg)
        const unsigned short* g =
            Wt + (size_t)(n0 + bn) * K + k0 + bk * 8;
        __builtin_amdgcn_global_load_lds(
            (const __attribute__((address_space(1))) void*)g,
            (__attribute__((address_space(3))) void*)(Bs + sbase * 8), 16, 0, 0);
      }
      __syncthreads();

#pragma unroll
      for (int kk = 0; kk < 2; ++kk) {
        bf16x8 a[2], b[2];
#pragma unroll
        for (int tm = 0; tm < 2; ++tm) {
          const int row = wr * 32 + tm * 16 + c;
          a[tm] = *(const bf16x8*)(As + (((kk * 4 + q) * 64) + row) * 8);
        }
#pragma unroll
        for (int tn = 0; tn < 2; ++tn) {
          const int n = wc * 32 + tn * 16 + c;
          b[tn] = *(const bf16x8*)(Bs + (n * 8 + ((kk * 4 + q) ^ (n & 7))) * 8);
        }
#pragma unroll
        for (int tm = 0; tm < 2; ++tm)
#pragma unroll
          for (int tn = 0; tn < 2; ++tn)
            acc[tm][tn] = __builtin_amdgcn_mfma_f32_16x16x32_bf16(
                a[tm], b[tn], acc[tm][tn], 0, 0, 0);
      }
      __syncthreads();
    }

    // C/D mapping: col=lane&15, row=quad*4+reg ; unscaled store
#pragma unroll
    for (int tm = 0; tm < 2; ++tm) {
#pragma unroll
      for (int r = 0; r < 4; ++r) {
        const int grow = m0 + wr * 32 + tm * 16 + q * 4 + r;
#pragma unroll
        for (int tn = 0; tn < 2; ++tn) {
          const int gcol = n0 + wc * 32 + tn * 16 + c;
          Hs[(size_t)grow * N + gcol] = f2bf(acc[tm][tn][r]);
        }
      }
    }
    return;
  }

  // ---- build_ell: one wave per node, popcount + lane prefix-scan.
  {
    const int wave = tid >> 6, lane = tid & 63;
    const int node = (bid - gemm_blocks) * 4 + wave;
    const unsigned* __restrict__ row = mask + (size_t)node * words;
    unsigned short* __restrict__ out = ell + (size_t)node * ELL_STRIDE;

    int running = 0;
    for (int r = 0; r < words; r += 64) {
      const int w = r + lane;
      unsigned bits = row[w];
      const int cnt = __popc(bits);
      int x = cnt;
#pragma unroll
      for (int d = 1; d < 64; d <<= 1) {
        int y = __shfl_up(x, d, 64);
        if (lane >= d) x += y;
      }
      int pos = running + x - cnt;
      while (bits) {
        const int b = __builtin_ctz(bits);
        bits &= bits - 1;
        if (pos < ELL_STRIDE) out[pos] = (unsigned short)((w << 5) + b);
        ++pos;
      }
      running += __shfl(x, 63, 64);
    }
    // self entry at [running], pads (index M -> dinv 0, zero row) after
    for (int p = running + lane; p < ELL_STRIDE; p += 64)
      out[p] = (unsigned short)(p == running ? node : M);
    if (lane == 0) {
      const int dd = running + 1;  // + self
      deg[node] = dd < ELL_STRIDE ? dd : ELL_STRIDE;
      dinv[node] = rsqrtf((float)running + 1.0f);
    }
  }
}

// ---- spmm: grid n/4 blocks, wave = one node, FULL D per entry.
// 64 lanes x 16B = 1KB = one full Hs row per iteration, fully coalesced.
// (byte_offset = j*2D, dinv[j]) staged once per wave as packed uint2 in LDS
// -> one broadcast ds_read_b64 + one v_add per iter on the gather path.
// Each lane owns 8 output columns -> no cross-lane reduce at all.
// 8192 waves total = 8/SIMD at 32 VGPR -> full occupancy; ~66 iters/wave.
__global__ __launch_bounds__(256) void spmm_kernel(
    const unsigned short* __restrict__ ell, const int* __restrict__ deg,
    const float* __restrict__ dinv, const unsigned short* __restrict__ Hs,
    const float* __restrict__ bias, float* __restrict__ out, int n, int D) {
  __shared__ uint2 ji[4][ELL_STRIDE];
  const int wave = threadIdx.x >> 6, lane = threadIdx.x & 63;
  const int i = blockIdx.x * 4 + wave;  // n divisible by 4
  const unsigned rowbytes = (unsigned)(D * 2);

  {  // stage (byte offset, dinv[j]) — 2 entries per lane; dinv is 32KB -> L1
    const unsigned j0 = ell[(size_t)i * ELL_STRIDE + lane];
    const unsigned j1 = ell[(size_t)i * ELL_STRIDE + 64 + lane];
    ji[wave][lane] = make_uint2(j0 * rowbytes, __float_as_uint(dinv[j0]));
    ji[wave][64 + lane] = make_uint2(j1 * rowbytes, __float_as_uint(dinv[j1]));
  }
  const int d = deg[i];            // includes the self entry
  const float di = dinv[i];
  const int kmax = (d + 7) & ~7;   // pads (dinv 0, zero row) cover the tail

  const char* __restrict__ hb = (const char*)(Hs + lane * 8);  // 16B/lane
  float acc[8] = {0.f, 0.f, 0.f, 0.f, 0.f, 0.f, 0.f, 0.f};

#pragma unroll 8
  for (int k = 0; k < kmax; ++k) {
    const uint2 e = ji[wave][k];  // uniform addr -> LDS broadcast
    const float dj = __uint_as_float(e.y);
    const uint4 hv = *(const uint4*)(hb + e.x);
    acc[0] += dj * bflo(hv.x); acc[1] += dj * bfhi(hv.x);
    acc[2] += dj * bflo(hv.y); acc[3] += dj * bfhi(hv.y);
    acc[4] += dj * bflo(hv.z); acc[5] += dj * bfhi(hv.z);
    acc[6] += dj * bflo(hv.w); acc[7] += dj * bfhi(hv.w);
  }

  const float4 b0 = *(const float4*)(bias + lane * 8);
  const float4 b1 = *(const float4*)(bias + lane * 8 + 4);
  float* op = out + (size_t)i * D + lane * 8;
  float4 o0, o1;
  o0.x = di * acc[0] + b0.x; o0.y = di * acc[1] + b0.y;
  o0.z = di * acc[2] + b0.z; o0.w = di * acc[3] + b0.w;
  o1.x = di * acc[4] + b1.x; o1.y = di * acc[5] + b1.y;
  o1.z = di * acc[6] + b1.z; o1.w = di * acc[7] + b1.w;
  *(float4*)op = o0;
  *(float4*)(op + 4) = o1;
}

extern "C" void kernel_launch(void* const* d_in, const int* in_sizes, int n_in,
                              void* d_out, int out_size, void* d_ws, size_t ws_size,
                              hipStream_t stream) {
  const float* x    = (const float*)d_in[0];
  const int*   ei   = (const int*)d_in[1];
  const float* W    = (const float*)d_in[2];
  const float* bias = (const float*)d_in[3];
  float* out = (float*)d_out;

  const int d_out_dim = in_sizes[3];             // 512
  const int d_in_dim  = in_sizes[2] / d_out_dim; // 512
  const int n_nodes   = in_sizes[0] / d_in_dim;  // 8192
  const int n_edges   = in_sizes[1] / 2;         // 262144
  const int words     = (n_nodes + 31) / 32;     // 256

  // workspace layout (bytes)
  char* ws = (char*)d_ws;
  size_t off = 0;
  unsigned* mask = (unsigned*)(ws + off); off += (size_t)n_nodes * words * 4;       // 8 MB
  int* deg       = (int*)(ws + off);      off += (size_t)n_nodes * 4;               // 32 KB
  float* dinv    = (float*)(ws + off);    off += (size_t)(n_nodes + 1) * 4;         // 32 KB + pad
  unsigned short* ell = (unsigned short*)(ws + off); off += (size_t)n_nodes * ELL_STRIDE * 2; // 2 MB
  unsigned short* xb  = (unsigned short*)(ws + off); off += (size_t)n_nodes * d_in_dim * 2;   // 8 MB
  unsigned short* Wt  = (unsigned short*)(ws + off); off += (size_t)d_in_dim * d_out_dim * 2; // 512 KB
  unsigned short* Hs  = (unsigned short*)(ws + off);
  off += (size_t)(n_nodes + 1) * d_out_dim * 2;  // 8 MB + pad row

  hipMemsetAsync(mask, 0, (size_t)n_nodes * words * 4, stream);

  const int edge_blocks = (n_edges + 255) / 256;              // 1024
  const int n4 = n_nodes * d_in_dim / 4;
  const int cast_blocks = (n4 + 255) / 256;                   // 4096
  const int tr_blocks = (d_in_dim / 32) * (d_out_dim / 32);   // 256
  fused_front_kernel<<<edge_blocks + cast_blocks + tr_blocks + 1, 256, 0, stream>>>(
      ei, mask, n_edges, words, x, xb, n4, W, Wt, d_in_dim, d_out_dim,
      Hs, dinv, n_nodes, edge_blocks, cast_blocks, tr_blocks);

  const int nbx = d_out_dim / 64;                             // 8
  const int nbx_sh = 31 - __builtin_clz(nbx);                 // 3
  const int gemm_blocks = nbx * (n_nodes / 64);               // 1024
  const int ell_blocks = n_nodes / 4;                         // 2048
  fused_mid_kernel<<<gemm_blocks + ell_blocks, 256, 0, stream>>>(
      xb, Wt, Hs, mask, ell, deg, dinv,
      n_nodes, d_out_dim, d_in_dim, words, gemm_blocks, nbx_sh);

  spmm_kernel<<<n_nodes / 4, 256, 0, stream>>>(ell, deg, dinv, Hs, bias, out,
                                               n_nodes, d_out_dim);
}